// Round 13
// baseline (62.579 us; speedup 1.0000x reference)
//
#include <hip/hip_runtime.h>

#define N_GROUPS 4096
#define K_POS 4
#define HID 256
#define M_NEG 256
#define KDIM 768  // (K_POS-1)*HID
#define N_EMB (N_GROUPS * K_POS)

typedef __attribute__((ext_vector_type(4))) float f32x4;
typedef __attribute__((ext_vector_type(4))) int i32x4;

#define QSCALE 32.0f            // emb & pred quant scale
#define WSCALE 512.0f           // W quant scale
#define QDESCALE (1.0f / (QSCALE * QSCALE))
#define GDESCALE (1.0f / (QSCALE * WSCALE))

__device__ inline int q8(float x, float scale) {
  int q = __float2int_rn(x * scale);
  return max(-127, min(127, q));
}
__device__ inline int pack4(float a, float b, float c, float d, float s) {
  return (q8(a, s) & 0xff) | ((q8(b, s) & 0xff) << 8) |
         ((q8(c, s) & 0xff) << 16) | ((q8(d, s) & 0xff) << 24);
}
__device__ inline int pack4v(const float4 v, float s) {
  return pack4(v.x, v.y, v.z, v.w, s);
}
// signed i8 lane extraction
__device__ inline int sb(int v, int k) { return (v << (24 - 8 * k)) >> 24; }

// ---------------- Kernel 0: W fp32 -> i8 (scale 512) ----------------
#define N4_W (KDIM * HID / 4)    // 49152 -> 192 blocks
__global__ __launch_bounds__(256) void convert_w(
    const float* __restrict__ W, int* __restrict__ WQ) {
  const int i = blockIdx.x * 256 + threadIdx.x;
  const float4 v = ((const float4*)W)[i];
  WQ[i] = pack4v(v, WSCALE);
}

// ---------------- Kernel 1: fused emb-quant + predicts GEMM -> embQ, predQ ----------
// grid (64,4), 4 waves. Wave wv owns row-tile mt = bx*4+wv (16 A-rows); reads fp32
// emb, quantizes A in-register (12 x i32x4). y==0 blocks also write embQ:
//   hist of group m  = embedding rows 4m..4m+2 = ints [m*256, m*256+192)
//   target of group m = embedding row 4m+3     = ints [m*256+192, m*256+256)
// Then 4 col-tiles (B from WQ) with A held in VGPRs; epilogue transposes the
// 16x16 tile via per-wave LDS and writes predQ (i8, row-major packing).
__global__ __launch_bounds__(256) void gemm_fused(
    const float* __restrict__ emb, const int* __restrict__ WQ,
    const float* __restrict__ bias, int* __restrict__ embQ,
    int* __restrict__ predQ) {
  const int wv = threadIdx.x >> 6, l = threadIdx.x & 63;
  const int mt = blockIdx.x * 4 + wv;   // 0..255 row-tile
  const int nt0 = blockIdx.y * 4;       // first of 4 col-tiles
  const int r = l & 15, g = l >> 4;
  __shared__ float sT[4][16 * 16];      // per-wave transpose buffer

  const int m = mt * 16 + r;            // A row (group index), 0..4095
  // A: fp32 hist elems [kk*64 + g*16, +16) -> quantize (same packing as embQ)
  const float* Af = emb + (size_t)m * (K_POS * HID) + g * 16;
  i32x4 a[12];
#pragma unroll
  for (int kk = 0; kk < 12; ++kk) {
    const float4 f0 = *(const float4*)(Af + kk * 64);
    const float4 f1 = *(const float4*)(Af + kk * 64 + 4);
    const float4 f2 = *(const float4*)(Af + kk * 64 + 8);
    const float4 f3 = *(const float4*)(Af + kk * 64 + 12);
    i32x4 p = {pack4v(f0, QSCALE), pack4v(f1, QSCALE), pack4v(f2, QSCALE), pack4v(f3, QSCALE)};
    a[kk] = p;
  }

  if (blockIdx.y == 0) {
    // hist slices: ints [m*256 + kk*16 + g*4, +4)  (bitwise = a convert pass)
#pragma unroll
    for (int kk = 0; kk < 12; ++kk)
      *(i32x4*)(embQ + (size_t)m * 256 + kk * 16 + g * 4) = a[kk];
    // target rows: thread t -> group row = bx*64 + (t>>2), quarter part = t&3
    // (64 floats = 16 ints per thread, full 256-float coverage)
    const int row = blockIdx.x * 64 + (threadIdx.x >> 2);
    const int part = threadIdx.x & 3;
#pragma unroll
    for (int u = 0; u < 4; ++u) {
      const float* tf = emb + (size_t)row * (K_POS * HID) + KDIM + part * 64 + u * 16;
      i32x4 tq = {pack4v(*(const float4*)(tf), QSCALE),
                  pack4v(*(const float4*)(tf + 4), QSCALE),
                  pack4v(*(const float4*)(tf + 8), QSCALE),
                  pack4v(*(const float4*)(tf + 12), QSCALE)};
      *(i32x4*)(embQ + (size_t)row * 256 + 192 + part * 16 + u * 4) = tq;
    }
  }

#pragma unroll
  for (int j = 0; j < 4; ++j) {
    const int nt = nt0 + j;
    const int* B = WQ + (size_t)(nt * 16 + r) * (KDIM / 4) + g * 4;
    i32x4 acc = {0, 0, 0, 0};
#pragma unroll
    for (int kk = 0; kk < 12; ++kk) {
      const i32x4 b = *(const i32x4*)(B + kk * 16);
      acc = __builtin_amdgcn_mfma_i32_16x16x64_i8(a[kk], b, acc, 0, 0, 0);
    }
    // C/D: col = r, row = g*4+i.  Stage f32 into [row][col], repack by rows.
    const float bb = bias[nt * 16 + r];
#pragma unroll
    for (int i = 0; i < 4; ++i)
      sT[wv][(g * 4 + i) * 16 + r] = (float)acc[i] * GDESCALE + bb;
    const int row = l >> 2, cb = l & 3;  // lane packs 4 consecutive cols of one row
    const float4 v = *(const float4*)&sT[wv][row * 16 + cb * 4];
    predQ[(size_t)(mt * 16 + row) * (HID / 4) + nt * 4 + cb] =
        pack4v(v, QSCALE);
  }
}

// ---------------- Kernel 2: negative logits via i8 MFMA, 2 waves per row ------------
// Wave owns half a row (128 negs = 8 tiles of 16). Per tile: 4x mfma_i32_16x16x64_i8.
// B-fragment lane l: row idx[l&15], bytes [kk*64 + (l>>4)*16, +16) -> one dwordx4
// per lane; lanes {c,c+16,c+32,c+48} cover one 64B line. A = predQ row (same
// (g,byte)->k packing as embQ => k-permutation-invariant).
__global__ __launch_bounds__(256) void loss_mfma(
    const int* __restrict__ embQ, const int* __restrict__ predQ,
    const int* __restrict__ neg_perm, float* __restrict__ row_loss) {
  const int tid = threadIdx.x;
  const int lane = tid & 63, wv = tid >> 6;
  const int n = blockIdx.x * 2 + (wv >> 1);   // 2 rows per block
  const int half = wv & 1;
  const int jl = lane & 15, g = lane >> 4;
  const int base = n * K_POS;
  __shared__ float smax[4], ssum[4], spos[4];

  // A fragments: predQ row n, ints [kk*16 + g*4, +4)
  const int* pq = predQ + (size_t)n * 64;
  i32x4 aQ[4];
#pragma unroll
  for (int kk = 0; kk < 4; ++kk) aQ[kk] = *(const i32x4*)(pq + kk * 16 + g * 4);

  // positive logit (half==0 wave only): i8 x i8 via VALU
  float posv = 0.f;
  if (half == 0) {
    const int va = pq[lane];
    const int vb = embQ[(size_t)(base + K_POS - 1) * 64 + lane];
    int d = sb(va, 0) * sb(vb, 0) + sb(va, 1) * sb(vb, 1) +
            sb(va, 2) * sb(vb, 2) + sb(va, 3) * sb(vb, 3);
    float s = (float)d;
    s += __shfl_xor(s, 1);  s += __shfl_xor(s, 2);  s += __shfl_xor(s, 4);
    s += __shfl_xor(s, 8);  s += __shfl_xor(s, 16); s += __shfl_xor(s, 32);
    posv = s * QDESCALE;
  }

  // hoist all 8 tile indices
  const int* nb = neg_perm + (size_t)n * M_NEG + half * 128;
  int idx[8];
#pragma unroll
  for (int jt = 0; jt < 8; ++jt) {
    const int j = nb[jt * 16 + jl];
    idx[jt] = j + (j >= base ? K_POS : 0);
  }

  float m0 = -INFINITY, s0 = 0.f, m1 = -INFINITY, s1 = 0.f;
#pragma unroll
  for (int t = 0; t < 8; t += 2) {
    const int* bp0 = embQ + (size_t)idx[t] * 64 + g * 4;
    const int* bp1 = embQ + (size_t)idx[t + 1] * 64 + g * 4;
    i32x4 acc0 = {0, 0, 0, 0}, acc1 = {0, 0, 0, 0};
#pragma unroll
    for (int kk = 0; kk < 4; ++kk) {
      const i32x4 b0 = *(const i32x4*)(bp0 + kk * 16);
      acc0 = __builtin_amdgcn_mfma_i32_16x16x64_i8(aQ[kk], b0, acc0, 0, 0, 0);
    }
#pragma unroll
    for (int kk = 0; kk < 4; ++kk) {
      const i32x4 b1 = *(const i32x4*)(bp1 + kk * 16);
      acc1 = __builtin_amdgcn_mfma_i32_16x16x64_i8(aQ[kk], b1, acc1, 0, 0, 0);
    }
    const float v0 = (float)acc0[0] * QDESCALE;
    const float v1 = (float)acc1[0] * QDESCALE;
    { const float mn = fmaxf(m0, v0); s0 = s0 * __expf(m0 - mn) + __expf(v0 - mn); m0 = mn; }
    { const float mn = fmaxf(m1, v1); s1 = s1 * __expf(m1 - mn) + __expf(v1 - mn); m1 = mn; }
  }

  // merge chains, then wave reduce (each negative counted by 4 lane-groups -> /4)
  float m = fmaxf(m0, m1);
  float s = s0 * __expf(m0 - m) + s1 * __expf(m1 - m);

  float gm = m;
  gm = fmaxf(gm, __shfl_xor(gm, 1));  gm = fmaxf(gm, __shfl_xor(gm, 2));
  gm = fmaxf(gm, __shfl_xor(gm, 4));  gm = fmaxf(gm, __shfl_xor(gm, 8));
  gm = fmaxf(gm, __shfl_xor(gm, 16)); gm = fmaxf(gm, __shfl_xor(gm, 32));
  float sr = s * __expf(m - gm);
  sr += __shfl_xor(sr, 1);  sr += __shfl_xor(sr, 2);  sr += __shfl_xor(sr, 4);
  sr += __shfl_xor(sr, 8);  sr += __shfl_xor(sr, 16); sr += __shfl_xor(sr, 32);
  sr *= 0.25f;

  if (lane == 0) { smax[wv] = gm; ssum[wv] = sr; spos[wv] = posv; }
  __syncthreads();

  if (half == 0 && lane == 0) {
    const float ma = smax[wv], mb = smax[wv + 1];
    const float sa = ssum[wv], sb2 = ssum[wv + 1];
    const float pv = spos[wv];
    const float mm = fmaxf(fmaxf(ma, mb), pv);
    const float tot = sa * __expf(ma - mm) + sb2 * __expf(mb - mm) + __expf(pv - mm);
    row_loss[n] = __logf(tot) + mm - pv;
  }
}

// ---------------- Kernel 3: deterministic mean (1024 thr, one float4 each) ----------
__global__ __launch_bounds__(1024) void reduce_mean(
    const float* __restrict__ row_loss, float* __restrict__ out) {
  const int tid = threadIdx.x;
  const int lane = tid & 63, wv = tid >> 6;
  const float4 v = ((const float4*)row_loss)[tid];
  float s = v.x + v.y + v.z + v.w;
  s += __shfl_xor(s, 1);  s += __shfl_xor(s, 2);  s += __shfl_xor(s, 4);
  s += __shfl_xor(s, 8);  s += __shfl_xor(s, 16); s += __shfl_xor(s, 32);
  __shared__ float red[16];
  if (lane == 0) red[wv] = s;
  __syncthreads();
  if (tid == 0) {
    float t = 0.f;
#pragma unroll
    for (int i = 0; i < 16; ++i) t += red[i];
    out[0] = t * (1.0f / N_GROUPS);
  }
}

extern "C" void kernel_launch(void* const* d_in, const int* in_sizes, int n_in,
                              void* d_out, int out_size, void* d_ws, size_t ws_size,
                              hipStream_t stream) {
  const float* emb = (const float*)d_in[0];
  const float* W = (const float*)d_in[1];
  const float* b = (const float*)d_in[2];
  const int* neg_perm = (const int*)d_in[4];
  float* out = (float*)d_out;

  int* embQ = (int*)d_ws;                                    // 4.2 MB (i8 packed)
  int* WQ = embQ + (size_t)N_EMB * HID / 4;                  // 0.2 MB
  int* predQ = WQ + (size_t)KDIM * HID / 4;                  // 1.05 MB (i8 packed)
  float* row_loss = (float*)(predQ + (size_t)N_GROUPS * HID / 4);  // 16 KB

  convert_w<<<N4_W / 256, 256, 0, stream>>>(W, WQ);
  gemm_fused<<<dim3(N_GROUPS / 64, 4), 256, 0, stream>>>(emb, WQ, b, embQ, predQ);
  loss_mfma<<<N_GROUPS / 2, 256, 0, stream>>>(embQ, predQ, neg_perm, row_loss);
  reduce_mean<<<1, 1024, 0, stream>>>(row_loss, out);
}